// Round 7
// baseline (705.106 us; speedup 1.0000x reference)
//
#include <hip/hip_runtime.h>
#include <hip/hip_cooperative_groups.h>
#include <hip/hip_bf16.h>

namespace cg = cooperative_groups;

#define NEG_SLOPE 0.2f
#define CAPG 8192       // per final-bucket slack (bk<<13), 1024 buckets of 128 nodes
#define CAPA 81920      // per-super slack (64 supers of 2048 nodes; mean 50K @ E=3.2M)

// ---------------------------------------------------------------------------
// GAT 2-layer, N=100k, E=3.2M (+self-loops analytic).
//
// R17: single cooperative kernel; sort ONCE, both layers use it.
// R16 post-mortem: l2_comb 52.6us with occupancy 41->56% => NO change; third
// consecutive null on combiner inner-structure. Invariant costs: per-combiner
// sort + per-combiner pairs read + 5 launches (+~30-40us unaccounted wall).
// R17: phases {cursor-init | scatterA | scatterB | sort+L1 (writes gsorted,
// bmeta) | L2 (reads sorted runs, NO sort)} in one kernel with grid.sync().
// Grid 512x1024 (launch_bounds(1024,8) => VGPR<=64 => 2 blocks/CU
// co-resident; runtime occupancy query; 256 fallback). Coop-launch failure
// -> R2 atomic fallback.
//
// R13 LESSON: LDS fp32 atomicAdd = CAS loop on gfx950; int LDS atomics only.
// Layer 1 collapses (IN==1, rank-1); softmax without max-subtraction
// (|logit| <~ 30; absmax 9.8e-4 across R2-R16).
// Pack: bufA = src | (d&2047)<<17 ; pairs/gsorted = src | (d&127)<<17.
// bmeta = offs | (cnt<<14). Guards: N<=131072. Fallback: R2 atomic path.
// ---------------------------------------------------------------------------

__global__ __launch_bounds__(1024, 8)
void fused_gat(const float* __restrict__ x, const int* __restrict__ ei,
               const float* __restrict__ W1, const float* __restrict__ as1,
               const float* __restrict__ ad1, const float* __restrict__ b1,
               const float* __restrict__ W2, const float* __restrict__ as2,
               const float* __restrict__ ad2, const float* __restrict__ b2,
               float* __restrict__ out,
               int* __restrict__ curA, int* __restrict__ curB,
               unsigned* __restrict__ bufA, unsigned* __restrict__ pairs,
               unsigned* __restrict__ gsorted, int* __restrict__ bmeta,
               float* __restrict__ als2, float* __restrict__ ald2,
               float* __restrict__ h2,
               int E, int N, int nbk)
{
    cg::grid_group grid = cg::this_grid();
    __shared__ unsigned sbuf[CAPG];                 // 32 KB
    __shared__ int hcnt[128], offs[128], hcur[128];
    __shared__ int cntA[64], baseA[64];
    __shared__ int cntB[16], baseB[16];
    __shared__ float xl[128];                       // x (phase C) / ald2 (phase D)

    int t = threadIdx.x;
    int B = blockIdx.x;
    int G = gridDim.x;

    // layer-1 consts, computed redundantly per thread (cheap)
    float S[4], D[4];
    #pragma unroll
    for (int h = 0; h < 4; ++h) {
        float s = 0.f, d = 0.f;
        #pragma unroll
        for (int c = 0; c < 8; ++c) {
            float w = W1[h * 8 + c];
            s += w * as1[h * 8 + c];
            d += w * ad1[h * 8 + c];
        }
        S[h] = s; D[h] = d;
    }

    // ---- phase 0: cursor init ----
    if (B == 0) {
        if (t < 64) curA[t] = t * CAPA;
        curB[t] = t << 13;
    }
    __threadfence();
    grid.sync();

    // ---- phase A: edges -> 64 super-buckets (2048 nodes each) ----
    {
        int chunk = (E + G - 1) / G;
        int lo = B * chunk;
        int hi = min(E, lo + chunk);
        const int* dei = ei + E;
        if (t < 64) cntA[t] = 0;
        __syncthreads();
        bool vec = ((E & 3) == 0);
        int lo4 = (lo + 3) & ~3;
        int end4 = hi & ~3;
        if (vec && end4 > lo4) {
            for (int e = lo + t; e < lo4; e += 1024) atomicAdd(&cntA[dei[e] >> 11], 1);
            const int4* dei4 = (const int4*)dei;
            for (int v = (lo4 >> 2) + t; v < (end4 >> 2); v += 1024) {
                int4 d = dei4[v];
                atomicAdd(&cntA[d.x >> 11], 1); atomicAdd(&cntA[d.y >> 11], 1);
                atomicAdd(&cntA[d.z >> 11], 1); atomicAdd(&cntA[d.w >> 11], 1);
            }
            for (int e = end4 + t; e < hi; e += 1024) atomicAdd(&cntA[dei[e] >> 11], 1);
        } else {
            for (int e = lo + t; e < hi; e += 1024) atomicAdd(&cntA[dei[e] >> 11], 1);
        }
        __syncthreads();
        if (t < 64) {
            int c = cntA[t];
            baseA[t] = c ? (atomicAdd(&curA[t], c) - t * CAPA) : 0;
            cntA[t] = 0;
        }
        __syncthreads();
        if (vec && end4 > lo4) {
            for (int e = lo + t; e < lo4; e += 1024) {
                int s = ei[e], d = dei[e]; int sp = d >> 11;
                int off = baseA[sp] + atomicAdd(&cntA[sp], 1);
                if (off < CAPA) bufA[sp * CAPA + off] = (unsigned)s | ((unsigned)(d & 2047) << 17);
            }
            const int4* sei4 = (const int4*)ei;
            const int4* dei4 = (const int4*)dei;
            for (int v = (lo4 >> 2) + t; v < (end4 >> 2); v += 1024) {
                int4 sv = sei4[v]; int4 dv = dei4[v];
                int s0 = dv.x >> 11, s1 = dv.y >> 11, s2 = dv.z >> 11, s3 = dv.w >> 11;
                int o0 = baseA[s0] + atomicAdd(&cntA[s0], 1);
                if (o0 < CAPA) bufA[s0 * CAPA + o0] = (unsigned)sv.x | ((unsigned)(dv.x & 2047) << 17);
                int o1 = baseA[s1] + atomicAdd(&cntA[s1], 1);
                if (o1 < CAPA) bufA[s1 * CAPA + o1] = (unsigned)sv.y | ((unsigned)(dv.y & 2047) << 17);
                int o2 = baseA[s2] + atomicAdd(&cntA[s2], 1);
                if (o2 < CAPA) bufA[s2 * CAPA + o2] = (unsigned)sv.z | ((unsigned)(dv.z & 2047) << 17);
                int o3 = baseA[s3] + atomicAdd(&cntA[s3], 1);
                if (o3 < CAPA) bufA[s3 * CAPA + o3] = (unsigned)sv.w | ((unsigned)(dv.w & 2047) << 17);
            }
            for (int e = end4 + t; e < hi; e += 1024) {
                int s = ei[e], d = dei[e]; int sp = d >> 11;
                int off = baseA[sp] + atomicAdd(&cntA[sp], 1);
                if (off < CAPA) bufA[sp * CAPA + off] = (unsigned)s | ((unsigned)(d & 2047) << 17);
            }
        } else {
            for (int e = lo + t; e < hi; e += 1024) {
                int s = ei[e], d = dei[e]; int sp = d >> 11;
                int off = baseA[sp] + atomicAdd(&cntA[sp], 1);
                if (off < CAPA) bufA[sp * CAPA + off] = (unsigned)s | ((unsigned)(d & 2047) << 17);
            }
        }
    }
    __threadfence();
    grid.sync();

    // ---- phase B: supers -> 16 final buckets each ----
    {
        int per = G >> 6;                 // blocks per super (4 or 8)
        int sp = B / per, part = B % per;
        int base = sp * CAPA;
        int fill = min(curA[sp] - base, CAPA);
        if (fill > 0) {
            int lo = (int)(((long long)fill * part) / per);
            int hi = (int)(((long long)fill * (part + 1)) / per);
            for (int c0 = lo; c0 < hi; c0 += 8192) {
                int cend = min(hi, c0 + 8192);
                if (t < 16) cntB[t] = 0;
                __syncthreads();
                for (int i = c0 + t; i < cend; i += 1024)
                    atomicAdd(&cntB[(bufA[base + i] >> 24) & 15], 1);
                __syncthreads();
                if (t < 16) {
                    int c = cntB[t];
                    int bkg = (sp << 4) + t;
                    baseB[t] = c ? (atomicAdd(&curB[bkg], c) - (bkg << 13)) : 0;
                    cntB[t] = 0;
                }
                __syncthreads();
                for (int i = c0 + t; i < cend; i += 1024) {
                    unsigned p = bufA[base + i];
                    int b16 = (p >> 24) & 15;
                    int off = baseB[b16] + atomicAdd(&cntB[b16], 1);
                    if (off < CAPG) pairs[(((sp << 4) + b16) << 13) + off] = p & 0x00FFFFFFu;
                }
                __syncthreads();
            }
        }
    }
    __threadfence();
    grid.sync();

    // ---- phase C: per-bucket LDS sort + layer-1; persist gsorted + bmeta ----
    int g = t >> 3, jj = t & 7;
    for (int bk = B; bk < nbk; bk += G) {
        __syncthreads();                        // prev iteration fully done
        int node0 = bk << 7;
        int nw = min(128, N - node0);
        if (t < 128) xl[t] = (t < nw) ? x[node0 + t] : 0.f;
        int base = bk << 13;
        int clen = min(curB[bk] - base, CAPG);
        unsigned pr[8];
        #pragma unroll
        for (int k = 0; k < 8; ++k) {
            int idx = t + (k << 10);
            pr[k] = (idx < clen) ? pairs[base + idx] : 0xFFFFFFFFu;
        }
        if (t < 128) hcnt[t] = 0;
        __syncthreads();
        #pragma unroll
        for (int k = 0; k < 8; ++k)
            if (pr[k] != 0xFFFFFFFFu) atomicAdd(&hcnt[pr[k] >> 17], 1);
        __syncthreads();
        if (t < 64) {                           // wave-0 shfl scan of 128 bins
            int h0 = hcnt[2 * t], h1 = hcnt[2 * t + 1];
            int s = h0 + h1, sc_ = s;
            #pragma unroll
            for (int o = 1; o < 64; o <<= 1) {
                int u = __shfl_up(sc_, o);
                if (t >= o) sc_ += u;
            }
            int excl = sc_ - s;
            offs[2 * t] = excl;          hcur[2 * t] = excl;
            offs[2 * t + 1] = excl + h0; hcur[2 * t + 1] = excl + h0;
        }
        __syncthreads();
        #pragma unroll
        for (int k = 0; k < 8; ++k)
            if (pr[k] != 0xFFFFFFFFu) {
                int loc = atomicAdd(&hcur[pr[k] >> 17], 1);
                sbuf[loc] = pr[k];
            }
        __syncthreads();
        // persist sorted runs + per-dst meta for phase D
        for (int i = t; i < clen; i += 1024) gsorted[base + i] = sbuf[i];
        if (t < 128) bmeta[(bk << 7) + t] = offs[t] | (hcnt[t] << 14);
        // layer-1 accumulate: 8 lanes own dst g
        float xd = xl[g];
        float sacc[4] = {0.f, 0.f, 0.f, 0.f};
        float tacc[4] = {0.f, 0.f, 0.f, 0.f};
        int st = offs[g], en = st + hcnt[g];
        int i = st + jj;
        float xs0 = 0.f, xs1 = 0.f;
        if (i < en) xs0 = x[sbuf[i] & 131071u];
        if (i + 8 < en) xs1 = x[sbuf[i + 8] & 131071u];
        for (; i < en; i += 8) {
            float xs = xs0;
            xs0 = xs1;
            int i2 = i + 16;
            xs1 = (i2 < en) ? x[sbuf[i2] & 131071u] : 0.f;
            #pragma unroll
            for (int h = 0; h < 4; ++h) {
                float v = xs * S[h] + xd * D[h];
                v = (v > 0.f) ? v : NEG_SLOPE * v;
                float w = __expf(v);
                sacc[h] += w;
                tacc[h] = fmaf(w, xs, tacc[h]);
            }
        }
        #pragma unroll
        for (int h = 0; h < 4; ++h) {
            sacc[h] += __shfl_xor(sacc[h], 1); sacc[h] += __shfl_xor(sacc[h], 2);
            sacc[h] += __shfl_xor(sacc[h], 4);
            tacc[h] += __shfl_xor(tacc[h], 1); tacc[h] += __shfl_xor(tacc[h], 2);
            tacc[h] += __shfl_xor(tacc[h], 4);
        }
        if (jj == 0 && g < nw) {
            int n = node0 + g;
            float xn = xd;
            float o[8];
            #pragma unroll
            for (int c = 0; c < 8; ++c) o[c] = 0.f;
            #pragma unroll
            for (int h = 0; h < 4; ++h) {
                float v = xn * (S[h] + D[h]);       // self-loop
                v = (v > 0.f) ? v : NEG_SLOPE * v;
                float ww = __expf(v);
                float s1 = ww + sacc[h];
                float t1 = ww * xn + tacc[h];
                float tt = t1 / s1;
                #pragma unroll
                for (int c = 0; c < 8; ++c) {
                    float rr = fmaxf(tt * W1[h * 8 + c] + b1[h * 8 + c], 0.f);
                    #pragma unroll
                    for (int c2 = 0; c2 < 8; ++c2) o[c2] += rr * W2[(h * 8 + c) * 8 + c2];
                }
            }
            float as = 0.f, ad = 0.f;
            #pragma unroll
            for (int c = 0; c < 8; ++c) { as += o[c] * as2[c]; ad += o[c] * ad2[c]; }
            float4* hv = (float4*)&h2[(size_t)n * 8];
            hv[0] = make_float4(o[0], o[1], o[2], o[3]);
            hv[1] = make_float4(o[4], o[5], o[6], o[7]);
            als2[n] = as;
            ald2[n] = ad;
        }
    }
    __threadfence();
    grid.sync();

    // ---- phase D: layer-2 from persisted sorted runs (no sort) ----
    for (int bk = B; bk < nbk; bk += G) {
        __syncthreads();
        int node0 = bk << 7;
        int nw = min(128, N - node0);
        if (t < 128) xl[t] = (t < nw) ? ald2[node0 + t] : 0.f;
        __syncthreads();
        int base = bk << 13;
        float adv = xl[g];
        int pk = bmeta[(bk << 7) + g];
        int st = pk & 16383, cgn = pk >> 14;
        const unsigned* run = gsorted + base + st;
        float acc[9];
        #pragma unroll
        for (int c = 0; c < 9; ++c) acc[c] = 0.f;
        int i = jj;
        float a0 = 0.f, a1 = 0.f;
        float4 hA0 = make_float4(0,0,0,0), hB0 = hA0, hA1 = hA0, hB1 = hA0;
        if (i < cgn) {
            int s0 = (int)(run[i] & 131071u);
            a0 = als2[s0];
            const float4* q = (const float4*)&h2[(size_t)s0 * 8];
            hA0 = q[0]; hB0 = q[1];
        }
        if (i + 8 < cgn) {
            int s1 = (int)(run[i + 8] & 131071u);
            a1 = als2[s1];
            const float4* q = (const float4*)&h2[(size_t)s1 * 8];
            hA1 = q[0]; hB1 = q[1];
        }
        for (; i < cgn; i += 8) {
            float a = a0; float4 hA = hA0, hB = hB0;
            a0 = a1; hA0 = hA1; hB0 = hB1;
            int i2 = i + 16;
            if (i2 < cgn) {
                int s2 = (int)(run[i2] & 131071u);
                a1 = als2[s2];
                const float4* q = (const float4*)&h2[(size_t)s2 * 8];
                hA1 = q[0]; hB1 = q[1];
            } else {
                a1 = 0.f;
            }
            float v = a + adv;
            v = (v > 0.f) ? v : NEG_SLOPE * v;
            float w = __expf(v);
            acc[0] += w;
            acc[1] = fmaf(w, hA.x, acc[1]); acc[2] = fmaf(w, hA.y, acc[2]);
            acc[3] = fmaf(w, hA.z, acc[3]); acc[4] = fmaf(w, hA.w, acc[4]);
            acc[5] = fmaf(w, hB.x, acc[5]); acc[6] = fmaf(w, hB.y, acc[6]);
            acc[7] = fmaf(w, hB.z, acc[7]); acc[8] = fmaf(w, hB.w, acc[8]);
        }
        #pragma unroll
        for (int c = 0; c < 9; ++c) {
            acc[c] += __shfl_xor(acc[c], 1);
            acc[c] += __shfl_xor(acc[c], 2);
            acc[c] += __shfl_xor(acc[c], 4);
        }
        if (jj == 0 && g < nw) {
            int n = node0 + g;
            float v = als2[n] + adv;              // self-loop
            v = (v > 0.f) ? v : NEG_SLOPE * v;
            float ww = __expf(v);
            const float4* hv = (const float4*)&h2[(size_t)n * 8];
            float4 ha0 = hv[0], hb0 = hv[1];
            float s2v = acc[0] + ww;
            float inv = 1.f / s2v;
            float4* ov = (float4*)&out[(size_t)n * 8];
            ov[0] = make_float4((acc[1] + ww * ha0.x) * inv + b2[0],
                                (acc[2] + ww * ha0.y) * inv + b2[1],
                                (acc[3] + ww * ha0.z) * inv + b2[2],
                                (acc[4] + ww * ha0.w) * inv + b2[3]);
            ov[1] = make_float4((acc[5] + ww * hb0.x) * inv + b2[4],
                                (acc[6] + ww * hb0.y) * inv + b2[5],
                                (acc[7] + ww * hb0.z) * inv + b2[6],
                                (acc[8] + ww * hb0.w) * inv + b2[7]);
        }
    }
}

// ---------------- fallback path (R2, atomic-based; known-correct) ----------------

__global__ void prep_consts(const float* __restrict__ W1,
                            const float* __restrict__ as1,
                            const float* __restrict__ ad1,
                            float* __restrict__ consts) {
    int t = threadIdx.x;
    if (t >= 8) return;
    int h = t & 3;
    const float* a = (t < 4) ? as1 : ad1;
    float s = 0.f;
    #pragma unroll
    for (int c = 0; c < 8; ++c)
        s += W1[h * 8 + c] * a[h * 8 + c];
    consts[t] = s;
}

__global__ void edge_pass1(const int* __restrict__ ei, const float* __restrict__ x,
                           const float* __restrict__ consts,
                           float* __restrict__ s1, float* __restrict__ t1, int E, int N) {
    int e = blockIdx.x * blockDim.x + threadIdx.x;
    if (e >= E + N) return;
    int src, dst;
    if (e < E) { src = ei[e]; dst = ei[E + e]; }
    else       { src = dst = e - E; }
    float xs = x[src], xd = x[dst];
    #pragma unroll
    for (int h = 0; h < 4; ++h) {
        float v = xs * consts[h] + xd * consts[4 + h];
        v = (v > 0.f) ? v : NEG_SLOPE * v;
        float w = __expf(v);
        atomicAdd(&s1[dst * 4 + h], w);
        atomicAdd(&t1[dst * 4 + h], w * xs);
    }
}

__global__ void node_mid(const float* __restrict__ s1, const float* __restrict__ t1,
                         const float* __restrict__ W1, const float* __restrict__ b1,
                         const float* __restrict__ W2,
                         const float* __restrict__ as2, const float* __restrict__ ad2,
                         float* __restrict__ h2, float* __restrict__ als2,
                         float* __restrict__ ald2, int N) {
    int n = blockIdx.x * blockDim.x + threadIdx.x;
    if (n >= N) return;
    float o[8];
    #pragma unroll
    for (int c = 0; c < 8; ++c) o[c] = 0.f;
    #pragma unroll
    for (int h = 0; h < 4; ++h) {
        float t = t1[n * 4 + h] / s1[n * 4 + h];
        #pragma unroll
        for (int c = 0; c < 8; ++c) {
            float r = fmaxf(t * W1[h * 8 + c] + b1[h * 8 + c], 0.f);
            #pragma unroll
            for (int c2 = 0; c2 < 8; ++c2) o[c2] += r * W2[(h * 8 + c) * 8 + c2];
        }
    }
    float as = 0.f, ad = 0.f;
    #pragma unroll
    for (int c = 0; c < 8; ++c) { h2[n * 8 + c] = o[c]; as += o[c] * as2[c]; ad += o[c] * ad2[c]; }
    als2[n] = as; ald2[n] = ad;
}

__global__ void edge_pass2(const int* __restrict__ ei, const float* __restrict__ als2,
                           const float* __restrict__ ald2, const float* __restrict__ h2,
                           float* __restrict__ s2, float* __restrict__ acc2, int E, int N) {
    int e = blockIdx.x * blockDim.x + threadIdx.x;
    if (e >= E + N) return;
    int src, dst;
    if (e < E) { src = ei[e]; dst = ei[E + e]; }
    else       { src = dst = e - E; }
    float v = als2[src] + ald2[dst];
    v = (v > 0.f) ? v : NEG_SLOPE * v;
    float w = __expf(v);
    atomicAdd(&s2[dst], w);
    const float4* hs = (const float4*)&h2[src * 8];
    float4 a = hs[0], bq = hs[1];
    float* acc = &acc2[dst * 8];
    atomicAdd(&acc[0], w * a.x);  atomicAdd(&acc[1], w * a.y);
    atomicAdd(&acc[2], w * a.z);  atomicAdd(&acc[3], w * a.w);
    atomicAdd(&acc[4], w * bq.x); atomicAdd(&acc[5], w * bq.y);
    atomicAdd(&acc[6], w * bq.z); atomicAdd(&acc[7], w * bq.w);
}

__global__ void node_out(const float* __restrict__ s2, const float* __restrict__ acc2,
                         const float* __restrict__ b2, float* __restrict__ out, int N) {
    int i = blockIdx.x * blockDim.x + threadIdx.x;
    if (i >= N * 8) return;
    out[i] = acc2[i] / s2[i >> 3] + b2[i & 7];
}

// ---------------------------------------------------------------------------

extern "C" void kernel_launch(void* const* d_in, const int* in_sizes, int n_in,
                              void* d_out, int out_size, void* d_ws, size_t ws_size,
                              hipStream_t stream) {
    const float* x   = (const float*)d_in[0];
    const int*   ei  = (const int*)d_in[1];
    const float* W1  = (const float*)d_in[2];
    const float* as1 = (const float*)d_in[3];
    const float* ad1 = (const float*)d_in[4];
    const float* b1  = (const float*)d_in[5];
    const float* W2  = (const float*)d_in[6];
    const float* as2 = (const float*)d_in[7];
    const float* ad2 = (const float*)d_in[8];
    const float* b2  = (const float*)d_in[9];
    float* out = (float*)d_out;

    const int N = in_sizes[0];          // 100000
    const int E = in_sizes[1] / 2;      // 3200000
    const int NBK = (N + 127) >> 7;     // 782 buckets of 128 nodes

    float* ws = (float*)d_ws;
    size_t need = ((size_t)64 + 1024 + 131072 + 10 * (size_t)N
                   + 2 * (size_t)1024 * CAPG + (size_t)64 * CAPA) * sizeof(float);

    bool fused_ok = false;
    if (N <= 131072 && ws_size >= need) {
        int*      curA    = (int*)ws;                        // 64
        int*      curB    = curA + 64;                       // 1024
        int*      bmeta   = curB + 1024;                     // 131072
        float*    als2    = (float*)(bmeta + 131072);        // N
        float*    ald2    = als2 + N;                        // N
        float*    h2      = ald2 + N;                        // 8N
        unsigned* pairs   = (unsigned*)(h2 + 8 * (size_t)N); // 1024*CAPG
        unsigned* gsorted = pairs + (size_t)1024 * CAPG;     // 1024*CAPG
        unsigned* bufA    = gsorted + (size_t)1024 * CAPG;   // 64*CAPA

        int maxb = 0;
        hipError_t qerr = hipOccupancyMaxActiveBlocksPerMultiprocessor(
            &maxb, (const void*)fused_gat, 1024, 0);
        int gridsz = (qerr == hipSuccess && maxb >= 2) ? 512 : 256;

        int e_ = E, n_ = N, nbk_ = NBK;
        void* args[] = { (void*)&x, (void*)&ei, (void*)&W1, (void*)&as1,
                         (void*)&ad1, (void*)&b1, (void*)&W2, (void*)&as2,
                         (void*)&ad2, (void*)&b2, (void*)&out,
                         (void*)&curA, (void*)&curB, (void*)&bufA,
                         (void*)&pairs, (void*)&gsorted, (void*)&bmeta,
                         (void*)&als2, (void*)&ald2, (void*)&h2,
                         (void*)&e_, (void*)&n_, (void*)&nbk_ };
        hipError_t lerr = hipLaunchCooperativeKernel(
            (const void*)fused_gat, dim3(gridsz), dim3(1024), args, 0, stream);
        fused_ok = (lerr == hipSuccess);
    }

    if (!fused_ok) {
        // fallback: R2 atomic path (10.8 MB ws, known-correct)
        float* consts = ws;
        float* s1   = ws + 16;
        float* t1   = s1 + 4 * (size_t)N;
        float* h2   = t1 + 4 * (size_t)N;
        float* als2 = h2 + 8 * (size_t)N;
        float* ald2 = als2 + (size_t)N;
        float* s2   = ald2 + (size_t)N;
        float* acc2 = s2 + (size_t)N;

        hipMemsetAsync(ws, 0, (16 + 8 * (size_t)N) * sizeof(float), stream);
        hipMemsetAsync(s2, 0, 9 * (size_t)N * sizeof(float), stream);
        prep_consts<<<1, 64, 0, stream>>>(W1, as1, ad1, consts);
        int total = E + N;
        edge_pass1<<<(total + 255) / 256, 256, 0, stream>>>(ei, x, consts, s1, t1, E, N);
        node_mid<<<(N + 255) / 256, 256, 0, stream>>>(s1, t1, W1, b1, W2, as2, ad2, h2, als2, ald2, N);
        edge_pass2<<<(total + 255) / 256, 256, 0, stream>>>(ei, als2, ald2, h2, s2, acc2, E, N);
        node_out<<<(N * 8 + 255) / 256, 256, 0, stream>>>(s2, acc2, b2, out, N);
    }
}

// Round 8
// 209.725 us; speedup vs baseline: 3.3620x; 3.3620x over previous
//
#include <hip/hip_runtime.h>
#include <hip/hip_bf16.h>

#define NEG_SLOPE 0.2f
#define CAPS 8192       // sbuf capacity (full bucket, single-chunk sort)
#define CAPG 8192       // per final-bucket slack (bk<<13), 1024 buckets of 128 nodes
#define CAPA 81920      // per-super slack (64 supers of 2048 nodes)

// ---------------------------------------------------------------------------
// GAT 2-layer, N=100k, E=3.2M (+self-loops analytic).
//
// R18: separate kernels (R16 frame) + R17's sort-once dataflow + channel-
// parallel layer-2.
// R17 post-mortem (705us): cooperative fusion catastrophically serialized
// (VALU 3% @ 97% occupancy; grid.sync + threadfence across non-coherent
// per-XCD L2s). LESSON: launches are cheaper than grid-wide syncs here.
// But sort-once dataflow itself was sound (absmax improved to 4.9e-4).
// R18 changes vs R16:
//  - l1_comb: single-chunk sort (sbuf 8192; reg-stage 6144 + direct-read
//    rest), persists gsorted (coalesced) + bmeta (offs | cnt<<14).
//  - l2_comb: channel-parallel, NO sort: thread (g,j) owns channel j of dst
//    g; the 8 lanes of a group walk the same run: run[i]/als2[src] are
//    broadcast (1 line/group), h2[src*8+j] is 32B contiguous -> each wave
//    gather touches ~8 lines vs 64 in the old layout. No shfl reduce;
//    out written coalesced. Predicted l2 52.6 -> ~22us, total ~170us.
//
// R13 LESSON: LDS fp32 atomicAdd = CAS loop on gfx950; int LDS atomics only.
// Layer 1 collapses (IN==1, rank-1); softmax without max-subtraction
// (|logit| <~ 30; absmax ~1e-3 across R2-R17).
// Pack: bufA = src | (d&2047)<<17 ; pairs/gsorted = src | (d&127)<<17.
// Guards: N <= 131072. Fallback: R2 atomic path.
// ---------------------------------------------------------------------------

// 1 block, 1024 threads: init cursors + layer-1 consts.
__global__ void init_cc(int* __restrict__ curA, int* __restrict__ curB,
                        const float* __restrict__ W1,
                        const float* __restrict__ as1,
                        const float* __restrict__ ad1,
                        float* __restrict__ consts) {
    int t = threadIdx.x;
    if (t < 8) {
        int h = t & 3;
        const float* a = (t < 4) ? as1 : ad1;
        float s = 0.f;
        #pragma unroll
        for (int c = 0; c < 8; ++c)
            s += W1[h * 8 + c] * a[h * 8 + c];
        consts[t] = s;
    }
    if (t < 64) curA[t] = t * CAPA;
    curB[t] = t << 13;
}

// Pass A: scatter edges into 64 super-buckets (2048 nodes each).
__global__ void scatterA(const int* __restrict__ ei, int* __restrict__ curA,
                         unsigned int* __restrict__ bufA, int E) {
    __shared__ int cnt[64];
    __shared__ int basel[64];
    int t = threadIdx.x;
    int chunk = (E + gridDim.x - 1) / gridDim.x;
    int lo = blockIdx.x * chunk;
    int hi = min(E, lo + chunk);
    const int* dei = ei + E;
    if (t < 64) cnt[t] = 0;
    __syncthreads();
    bool vec = ((E & 3) == 0);
    int lo4 = (lo + 3) & ~3;
    int end4 = hi & ~3;
    if (vec && end4 > lo4) {
        for (int e = lo + t; e < lo4; e += 1024) atomicAdd(&cnt[dei[e] >> 11], 1);
        const int4* dei4 = (const int4*)dei;
        for (int v = (lo4 >> 2) + t; v < (end4 >> 2); v += 1024) {
            int4 d = dei4[v];
            atomicAdd(&cnt[d.x >> 11], 1); atomicAdd(&cnt[d.y >> 11], 1);
            atomicAdd(&cnt[d.z >> 11], 1); atomicAdd(&cnt[d.w >> 11], 1);
        }
        for (int e = end4 + t; e < hi; e += 1024) atomicAdd(&cnt[dei[e] >> 11], 1);
    } else {
        for (int e = lo + t; e < hi; e += 1024) atomicAdd(&cnt[dei[e] >> 11], 1);
    }
    __syncthreads();
    if (t < 64) {
        int c = cnt[t];
        basel[t] = c ? (atomicAdd(&curA[t], c) - t * CAPA) : 0;
        cnt[t] = 0;
    }
    __syncthreads();
    if (vec && end4 > lo4) {
        for (int e = lo + t; e < lo4; e += 1024) {
            int s = ei[e], d = dei[e]; int sp = d >> 11;
            int off = basel[sp] + atomicAdd(&cnt[sp], 1);
            if (off < CAPA) bufA[sp * CAPA + off] = (unsigned)s | ((unsigned)(d & 2047) << 17);
        }
        const int4* sei4 = (const int4*)ei;
        const int4* dei4 = (const int4*)dei;
        for (int v = (lo4 >> 2) + t; v < (end4 >> 2); v += 1024) {
            int4 sv = sei4[v]; int4 dv = dei4[v];
            int s0 = dv.x >> 11, s1 = dv.y >> 11, s2 = dv.z >> 11, s3 = dv.w >> 11;
            int o0 = basel[s0] + atomicAdd(&cnt[s0], 1);
            if (o0 < CAPA) bufA[s0 * CAPA + o0] = (unsigned)sv.x | ((unsigned)(dv.x & 2047) << 17);
            int o1 = basel[s1] + atomicAdd(&cnt[s1], 1);
            if (o1 < CAPA) bufA[s1 * CAPA + o1] = (unsigned)sv.y | ((unsigned)(dv.y & 2047) << 17);
            int o2 = basel[s2] + atomicAdd(&cnt[s2], 1);
            if (o2 < CAPA) bufA[s2 * CAPA + o2] = (unsigned)sv.z | ((unsigned)(dv.z & 2047) << 17);
            int o3 = basel[s3] + atomicAdd(&cnt[s3], 1);
            if (o3 < CAPA) bufA[s3 * CAPA + o3] = (unsigned)sv.w | ((unsigned)(dv.w & 2047) << 17);
        }
        for (int e = end4 + t; e < hi; e += 1024) {
            int s = ei[e], d = dei[e]; int sp = d >> 11;
            int off = basel[sp] + atomicAdd(&cnt[sp], 1);
            if (off < CAPA) bufA[sp * CAPA + off] = (unsigned)s | ((unsigned)(d & 2047) << 17);
        }
    } else {
        for (int e = lo + t; e < hi; e += 1024) {
            int s = ei[e], d = dei[e]; int sp = d >> 11;
            int off = basel[sp] + atomicAdd(&cnt[sp], 1);
            if (off < CAPA) bufA[sp * CAPA + off] = (unsigned)s | ((unsigned)(d & 2047) << 17);
        }
    }
}

// Pass B: 8 blocks per super; re-scatter into 16 final 128-node buckets.
__global__ void scatterB(const int* __restrict__ curA, int* __restrict__ curB,
                         const unsigned int* __restrict__ bufA,
                         unsigned int* __restrict__ pairs) {
    __shared__ int cnt[16];
    __shared__ int basel[16];
    int t = threadIdx.x;
    int sp = blockIdx.x >> 3;
    int part = blockIdx.x & 7;
    int base = sp * CAPA;
    int fill = min(curA[sp] - base, CAPA);
    if (fill <= 0) return;
    int lo = (fill * part) >> 3;
    int hi = (fill * (part + 1)) >> 3;
    for (int c0 = lo; c0 < hi; c0 += 8192) {
        int cend = min(hi, c0 + 8192);
        if (t < 16) cnt[t] = 0;
        __syncthreads();
        for (int i = c0 + t; i < cend; i += 1024)
            atomicAdd(&cnt[(bufA[base + i] >> 24) & 15], 1);
        __syncthreads();
        if (t < 16) {
            int c = cnt[t];
            int bkg = (sp << 4) + t;
            basel[t] = c ? (atomicAdd(&curB[bkg], c) - (bkg << 13)) : 0;
            cnt[t] = 0;
        }
        __syncthreads();
        for (int i = c0 + t; i < cend; i += 1024) {
            unsigned p = bufA[base + i];
            int b16 = (p >> 24) & 15;
            int off = basel[b16] + atomicAdd(&cnt[b16], 1);
            if (off < CAPG) pairs[(((sp << 4) + b16) << 13) + off] = p & 0x00FFFFFFu;
        }
        __syncthreads();
    }
}

// Layer-1: single-chunk sort + accumulate; persists gsorted + bmeta for L2.
__global__ __launch_bounds__(1024, 8)
void l1_comb(const float* __restrict__ x,
             const int* __restrict__ curB,
             const unsigned int* __restrict__ pairs,
             unsigned int* __restrict__ gsorted, int* __restrict__ bmeta,
             const float* __restrict__ consts,
             const float* __restrict__ W1, const float* __restrict__ b1,
             const float* __restrict__ W2,
             const float* __restrict__ as2, const float* __restrict__ ad2,
             float* __restrict__ h2, float* __restrict__ als2,
             float* __restrict__ ald2, int N) {
    __shared__ unsigned sbuf[CAPS];
    __shared__ int hcnt[128], offs[128], hcur[128];
    __shared__ float xl[128];
    int t = threadIdx.x;
    int bk = blockIdx.x;
    int node0 = bk << 7;
    int nw = min(128, N - node0);
    if (t < 128) xl[t] = (t < nw) ? x[node0 + t] : 0.f;
    float S[4], D[4];
    #pragma unroll
    for (int h = 0; h < 4; ++h) { S[h] = consts[h]; D[h] = consts[4 + h]; }
    int base = bk << 13;
    int clen = min(curB[bk] - base, CAPG);
    int clen6 = min(clen, 6144);
    int g = t >> 3, jj = t & 7;
    // stage first 6144 pairs in regs; remainder read direct (rare tail)
    unsigned pr[6];
    #pragma unroll
    for (int k = 0; k < 6; ++k) {
        int idx = t + (k << 10);
        pr[k] = (idx < clen6) ? pairs[base + idx] : 0xFFFFFFFFu;
    }
    if (t < 128) hcnt[t] = 0;
    __syncthreads();
    #pragma unroll
    for (int k = 0; k < 6; ++k)
        if (pr[k] != 0xFFFFFFFFu) atomicAdd(&hcnt[pr[k] >> 17], 1);
    for (int idx = 6144 + t; idx < clen; idx += 1024)
        atomicAdd(&hcnt[pairs[base + idx] >> 17], 1);
    __syncthreads();
    if (t < 64) {                          // wave-0 shfl scan of 128 bins
        int h0 = hcnt[2 * t], h1 = hcnt[2 * t + 1];
        int s = h0 + h1, sc_ = s;
        #pragma unroll
        for (int o = 1; o < 64; o <<= 1) {
            int u = __shfl_up(sc_, o);
            if (t >= o) sc_ += u;
        }
        int excl = sc_ - s;
        offs[2 * t] = excl;          hcur[2 * t] = excl;
        offs[2 * t + 1] = excl + h0; hcur[2 * t + 1] = excl + h0;
    }
    __syncthreads();
    #pragma unroll
    for (int k = 0; k < 6; ++k)
        if (pr[k] != 0xFFFFFFFFu) {
            int loc = atomicAdd(&hcur[pr[k] >> 17], 1);
            sbuf[loc] = pr[k];
        }
    for (int idx = 6144 + t; idx < clen; idx += 1024) {
        unsigned p = pairs[base + idx];
        int loc = atomicAdd(&hcur[p >> 17], 1);
        sbuf[loc] = p;
    }
    __syncthreads();
    // persist sorted runs + meta for layer-2
    for (int i = t; i < clen; i += 1024) gsorted[base + i] = sbuf[i];
    if (t < 128) bmeta[(bk << 7) + t] = offs[t] | (hcnt[t] << 14);
    // accumulate: 8 lanes own dst g, each 1/8 of the run, depth-2 prefetch
    float xd = xl[g];
    float sacc[4] = {0.f, 0.f, 0.f, 0.f};
    float tacc[4] = {0.f, 0.f, 0.f, 0.f};
    int st = offs[g], en = st + hcnt[g];
    int i = st + jj;
    float xs0 = 0.f, xs1 = 0.f;
    if (i < en) xs0 = x[sbuf[i] & 131071u];
    if (i + 8 < en) xs1 = x[sbuf[i + 8] & 131071u];
    for (; i < en; i += 8) {
        float xs = xs0;
        xs0 = xs1;
        int i2 = i + 16;
        xs1 = (i2 < en) ? x[sbuf[i2] & 131071u] : 0.f;
        #pragma unroll
        for (int h = 0; h < 4; ++h) {
            float v = xs * S[h] + xd * D[h];
            v = (v > 0.f) ? v : NEG_SLOPE * v;
            float w = __expf(v);
            sacc[h] += w;
            tacc[h] = fmaf(w, xs, tacc[h]);
        }
    }
    #pragma unroll
    for (int h = 0; h < 4; ++h) {
        sacc[h] += __shfl_xor(sacc[h], 1); sacc[h] += __shfl_xor(sacc[h], 2);
        sacc[h] += __shfl_xor(sacc[h], 4);
        tacc[h] += __shfl_xor(tacc[h], 1); tacc[h] += __shfl_xor(tacc[h], 2);
        tacc[h] += __shfl_xor(tacc[h], 4);
    }
    if (jj == 0 && g < nw) {
        int n = node0 + g;
        float xn = xd;
        float o[8];
        #pragma unroll
        for (int c = 0; c < 8; ++c) o[c] = 0.f;
        #pragma unroll
        for (int h = 0; h < 4; ++h) {
            float v = xn * (S[h] + D[h]);       // self-loop
            v = (v > 0.f) ? v : NEG_SLOPE * v;
            float ww = __expf(v);
            float s1 = ww + sacc[h];
            float t1 = ww * xn + tacc[h];
            float tt = t1 / s1;
            #pragma unroll
            for (int c = 0; c < 8; ++c) {
                float rr = fmaxf(tt * W1[h * 8 + c] + b1[h * 8 + c], 0.f);
                #pragma unroll
                for (int c2 = 0; c2 < 8; ++c2) o[c2] += rr * W2[(h * 8 + c) * 8 + c2];
            }
        }
        float as = 0.f, ad = 0.f;
        #pragma unroll
        for (int c = 0; c < 8; ++c) { as += o[c] * as2[c]; ad += o[c] * ad2[c]; }
        float4* hv = (float4*)&h2[(size_t)n * 8];
        hv[0] = make_float4(o[0], o[1], o[2], o[3]);
        hv[1] = make_float4(o[4], o[5], o[6], o[7]);
        als2[n] = as;
        ald2[n] = ad;
    }
}

// Layer-2: channel-parallel, no sort. Thread (g,j) owns channel j of dst g.
// Group's 8 lanes walk the same sorted run: run[i], als2[src] broadcast;
// h2[src*8+j] coalesced 32B/group; out written coalesced; no reduces.
__global__ __launch_bounds__(1024)
void l2_comb(const unsigned int* __restrict__ gsorted,
             const int* __restrict__ bmeta,
             const float* __restrict__ als2, const float* __restrict__ ald2,
             const float* __restrict__ h2, const float* __restrict__ b2,
             float* __restrict__ out, int N) {
    __shared__ float adl[128];
    int t = threadIdx.x;
    int bk = blockIdx.x;
    int node0 = bk << 7;
    int nw = min(128, N - node0);
    if (t < 128) adl[t] = (t < nw) ? ald2[node0 + t] : 0.f;
    __syncthreads();
    int g = t >> 3, j = t & 7;
    if (g >= nw) return;
    int base = bk << 13;
    int pk = bmeta[(bk << 7) + g];
    int st = pk & 16383, cgn = pk >> 14;
    const unsigned* run = gsorted + base + st;
    float adv = adl[g];
    float accv = 0.f, sw = 0.f;
    // depth-2 software pipeline: (a,h) for i and i+1, pair for i+2
    float a0 = 0.f, h0 = 0.f, a1 = 0.f, h1 = 0.f;
    unsigned p2 = 0u;
    if (cgn > 0) { int s = (int)(run[0] & 131071u); a0 = als2[s]; h0 = h2[(size_t)s * 8 + j]; }
    if (cgn > 1) { int s = (int)(run[1] & 131071u); a1 = als2[s]; h1 = h2[(size_t)s * 8 + j]; }
    if (cgn > 2) p2 = run[2];
    for (int i = 0; i < cgn; ++i) {
        float v = a0 + adv;
        v = (v > 0.f) ? v : NEG_SLOPE * v;
        float w = __expf(v);
        sw += w;
        accv = fmaf(w, h0, accv);
        a0 = a1; h0 = h1;
        int i2 = i + 2;
        if (i2 < cgn) {
            int s = (int)(p2 & 131071u);
            a1 = als2[s];
            h1 = h2[(size_t)s * 8 + j];
        }
        p2 = (i + 3 < cgn) ? run[i + 3] : 0u;
    }
    // self-loop + output (coalesced: 8 lanes cover one 32B row)
    int n = node0 + g;
    float v = als2[n] + adv;
    v = (v > 0.f) ? v : NEG_SLOPE * v;
    float ww = __expf(v);
    float hs = h2[(size_t)n * 8 + j];
    float s2v = sw + ww;
    out[(size_t)n * 8 + j] = (accv + ww * hs) / s2v + b2[j];
}

// ---------------- fallback path (R2, atomic-based; known-correct) ----------------

__global__ void prep_consts(const float* __restrict__ W1,
                            const float* __restrict__ as1,
                            const float* __restrict__ ad1,
                            float* __restrict__ consts) {
    int t = threadIdx.x;
    if (t >= 8) return;
    int h = t & 3;
    const float* a = (t < 4) ? as1 : ad1;
    float s = 0.f;
    #pragma unroll
    for (int c = 0; c < 8; ++c)
        s += W1[h * 8 + c] * a[h * 8 + c];
    consts[t] = s;
}

__global__ void edge_pass1(const int* __restrict__ ei, const float* __restrict__ x,
                           const float* __restrict__ consts,
                           float* __restrict__ s1, float* __restrict__ t1, int E, int N) {
    int e = blockIdx.x * blockDim.x + threadIdx.x;
    if (e >= E + N) return;
    int src, dst;
    if (e < E) { src = ei[e]; dst = ei[E + e]; }
    else       { src = dst = e - E; }
    float xs = x[src], xd = x[dst];
    #pragma unroll
    for (int h = 0; h < 4; ++h) {
        float v = xs * consts[h] + xd * consts[4 + h];
        v = (v > 0.f) ? v : NEG_SLOPE * v;
        float w = __expf(v);
        atomicAdd(&s1[dst * 4 + h], w);
        atomicAdd(&t1[dst * 4 + h], w * xs);
    }
}

__global__ void node_mid(const float* __restrict__ s1, const float* __restrict__ t1,
                         const float* __restrict__ W1, const float* __restrict__ b1,
                         const float* __restrict__ W2,
                         const float* __restrict__ as2, const float* __restrict__ ad2,
                         float* __restrict__ h2, float* __restrict__ als2,
                         float* __restrict__ ald2, int N) {
    int n = blockIdx.x * blockDim.x + threadIdx.x;
    if (n >= N) return;
    float o[8];
    #pragma unroll
    for (int c = 0; c < 8; ++c) o[c] = 0.f;
    #pragma unroll
    for (int h = 0; h < 4; ++h) {
        float t = t1[n * 4 + h] / s1[n * 4 + h];
        #pragma unroll
        for (int c = 0; c < 8; ++c) {
            float r = fmaxf(t * W1[h * 8 + c] + b1[h * 8 + c], 0.f);
            #pragma unroll
            for (int c2 = 0; c2 < 8; ++c2) o[c2] += r * W2[(h * 8 + c) * 8 + c2];
        }
    }
    float as = 0.f, ad = 0.f;
    #pragma unroll
    for (int c = 0; c < 8; ++c) { h2[n * 8 + c] = o[c]; as += o[c] * as2[c]; ad += o[c] * ad2[c]; }
    als2[n] = as; ald2[n] = ad;
}

__global__ void edge_pass2(const int* __restrict__ ei, const float* __restrict__ als2,
                           const float* __restrict__ ald2, const float* __restrict__ h2,
                           float* __restrict__ s2, float* __restrict__ acc2, int E, int N) {
    int e = blockIdx.x * blockDim.x + threadIdx.x;
    if (e >= E + N) return;
    int src, dst;
    if (e < E) { src = ei[e]; dst = ei[E + e]; }
    else       { src = dst = e - E; }
    float v = als2[src] + ald2[dst];
    v = (v > 0.f) ? v : NEG_SLOPE * v;
    float w = __expf(v);
    atomicAdd(&s2[dst], w);
    const float4* hs = (const float4*)&h2[src * 8];
    float4 a = hs[0], bq = hs[1];
    float* acc = &acc2[dst * 8];
    atomicAdd(&acc[0], w * a.x);  atomicAdd(&acc[1], w * a.y);
    atomicAdd(&acc[2], w * a.z);  atomicAdd(&acc[3], w * a.w);
    atomicAdd(&acc[4], w * bq.x); atomicAdd(&acc[5], w * bq.y);
    atomicAdd(&acc[6], w * bq.z); atomicAdd(&acc[7], w * bq.w);
}

__global__ void node_out(const float* __restrict__ s2, const float* __restrict__ acc2,
                         const float* __restrict__ b2, float* __restrict__ out, int N) {
    int i = blockIdx.x * blockDim.x + threadIdx.x;
    if (i >= N * 8) return;
    out[i] = acc2[i] / s2[i >> 3] + b2[i & 7];
}

// ---------------------------------------------------------------------------

extern "C" void kernel_launch(void* const* d_in, const int* in_sizes, int n_in,
                              void* d_out, int out_size, void* d_ws, size_t ws_size,
                              hipStream_t stream) {
    const float* x   = (const float*)d_in[0];
    const int*   ei  = (const int*)d_in[1];
    const float* W1  = (const float*)d_in[2];
    const float* as1 = (const float*)d_in[3];
    const float* ad1 = (const float*)d_in[4];
    const float* b1  = (const float*)d_in[5];
    const float* W2  = (const float*)d_in[6];
    const float* as2 = (const float*)d_in[7];
    const float* ad2 = (const float*)d_in[8];
    const float* b2  = (const float*)d_in[9];
    float* out = (float*)d_out;

    const int N = in_sizes[0];          // 100000
    const int E = in_sizes[1] / 2;      // 3200000
    const int NBK = (N + 127) >> 7;     // 782 buckets of 128 nodes

    float* ws = (float*)d_ws;
    size_t need = ((size_t)16 + 64 + 1024 + 131072 + 10 * (size_t)N
                   + 2 * (size_t)1024 * CAPG + (size_t)64 * CAPA) * sizeof(float);

    if (N <= 131072 && ws_size >= need) {
        float*    consts  = ws;                               // 16
        int*      curA    = (int*)(ws + 16);                  // 64
        int*      curB    = curA + 64;                        // 1024
        int*      bmeta   = curB + 1024;                      // 131072
        float*    als2    = (float*)(bmeta + 131072);         // N
        float*    ald2    = als2 + N;                         // N
        float*    h2      = ald2 + N;                         // 8N
        unsigned* pairs   = (unsigned*)(h2 + 8 * (size_t)N);  // 1024*CAPG
        unsigned* gsorted = pairs + (size_t)1024 * CAPG;      // 1024*CAPG
        unsigned* bufA    = gsorted + (size_t)1024 * CAPG;    // 64*CAPA

        init_cc<<<1, 1024, 0, stream>>>(curA, curB, W1, as1, ad1, consts);
        scatterA<<<256, 1024, 0, stream>>>(ei, curA, bufA, E);
        scatterB<<<512, 1024, 0, stream>>>(curA, curB, bufA, pairs);
        l1_comb<<<NBK, 1024, 0, stream>>>(x, curB, pairs, gsorted, bmeta, consts,
                                          W1, b1, W2, as2, ad2, h2, als2, ald2, N);
        l2_comb<<<NBK, 1024, 0, stream>>>(gsorted, bmeta, als2, ald2, h2, b2, out, N);
    } else {
        // fallback: R2 atomic path (10.8 MB ws, known-correct)
        float* consts = ws;
        float* s1   = ws + 16;
        float* t1   = s1 + 4 * (size_t)N;
        float* h2   = t1 + 4 * (size_t)N;
        float* als2 = h2 + 8 * (size_t)N;
        float* ald2 = als2 + (size_t)N;
        float* s2   = ald2 + (size_t)N;
        float* acc2 = s2 + (size_t)N;

        hipMemsetAsync(ws, 0, (16 + 8 * (size_t)N) * sizeof(float), stream);
        hipMemsetAsync(s2, 0, 9 * (size_t)N * sizeof(float), stream);
        prep_consts<<<1, 64, 0, stream>>>(W1, as1, ad1, consts);
        int total = E + N;
        edge_pass1<<<(total + 255) / 256, 256, 0, stream>>>(ei, x, consts, s1, t1, E, N);
        node_mid<<<(N + 255) / 256, 256, 0, stream>>>(s1, t1, W1, b1, W2, as2, ad2, h2, als2, ald2, N);
        edge_pass2<<<(total + 255) / 256, 256, 0, stream>>>(ei, als2, ald2, h2, s2, acc2, E, N);
        node_out<<<(N * 8 + 255) / 256, 256, 0, stream>>>(s2, acc2, b2, out, N);
    }
}

// Round 9
// 186.951 us; speedup vs baseline: 3.7716x; 1.1218x over previous
//
#include <hip/hip_runtime.h>
#include <hip/hip_bf16.h>

#define NEG_SLOPE 0.2f
#define CAPS 8192       // sbuf capacity (full bucket, single-chunk sort)
#define CAPG 8192       // per final-bucket slack (bk<<13), 1024 buckets of 128 nodes
#define CAPA 81920      // per-super slack (64 supers of 2048 nodes)

// ---------------------------------------------------------------------------
// GAT 2-layer, N=100k, E=3.2M (+self-loops analytic).
//
// R19: deep-batched gathers (MLP 2 -> 16/thread) + 512-thr single-round grid.
// R18 post-mortem: l2 63.9us @ VALU 29%, conflicts 0, FETCH 41.8MB -> the
// h2/als2 gather misses local-XCD L2 (h2 scattered across 8 XCDs) at
// ~500-900cyc, and the channel-parallel walk was SERIAL (trip x8) with only
// depth-2 prefetch = 2 outstanding loads vs ~900cyc. Whole combiner plateau
// R12-R18 (45-64us) = MLP-starved latency-bound gather. Also 1024-thr blocks
// -> 2 blocks/CU -> 1.53 grid rounds (tail waste).
// R19: (1) batch-8 gather loads into statically-indexed regs per step
// (l2: 8x als2 + 8x float2 h2 = 16 outstanding; l1: 8x x); (2) 512-thr
// blocks, launch_bounds(512,8) (VGPR<=64, 4 blocks/CU, 1024 slots >= 782
// -> single round). l2: 4 lanes/dst x 2 channels; l1: 4 lanes/dst.
// Predicted: l2 -> ~22-28us, l1 -> ~35us, total -> ~155-165us.
//
// R17 LESSON: grid-wide coop sync >> launch cost on MI355X; keep launches.
// R13 LESSON: LDS fp32 atomicAdd = CAS loop on gfx950; int LDS atomics only.
// Layer 1 collapses (IN==1, rank-1); softmax without max-subtraction
// (|logit| <~ 30; absmax ~1e-3 across R2-R18).
// Pack: bufA = src | (d&2047)<<17 ; pairs/gsorted = src | (d&127)<<17.
// bmeta = offs | (cnt<<14). Guards: N <= 131072. Fallback: R2 atomic path.
// ---------------------------------------------------------------------------

// 1 block, 1024 threads: init cursors + layer-1 consts.
__global__ void init_cc(int* __restrict__ curA, int* __restrict__ curB,
                        const float* __restrict__ W1,
                        const float* __restrict__ as1,
                        const float* __restrict__ ad1,
                        float* __restrict__ consts) {
    int t = threadIdx.x;
    if (t < 8) {
        int h = t & 3;
        const float* a = (t < 4) ? as1 : ad1;
        float s = 0.f;
        #pragma unroll
        for (int c = 0; c < 8; ++c)
            s += W1[h * 8 + c] * a[h * 8 + c];
        consts[t] = s;
    }
    if (t < 64) curA[t] = t * CAPA;
    curB[t] = t << 13;
}

// Pass A: scatter edges into 64 super-buckets (2048 nodes each).
__global__ void scatterA(const int* __restrict__ ei, int* __restrict__ curA,
                         unsigned int* __restrict__ bufA, int E) {
    __shared__ int cnt[64];
    __shared__ int basel[64];
    int t = threadIdx.x;
    int chunk = (E + gridDim.x - 1) / gridDim.x;
    int lo = blockIdx.x * chunk;
    int hi = min(E, lo + chunk);
    const int* dei = ei + E;
    if (t < 64) cnt[t] = 0;
    __syncthreads();
    bool vec = ((E & 3) == 0);
    int lo4 = (lo + 3) & ~3;
    int end4 = hi & ~3;
    if (vec && end4 > lo4) {
        for (int e = lo + t; e < lo4; e += 1024) atomicAdd(&cnt[dei[e] >> 11], 1);
        const int4* dei4 = (const int4*)dei;
        for (int v = (lo4 >> 2) + t; v < (end4 >> 2); v += 1024) {
            int4 d = dei4[v];
            atomicAdd(&cnt[d.x >> 11], 1); atomicAdd(&cnt[d.y >> 11], 1);
            atomicAdd(&cnt[d.z >> 11], 1); atomicAdd(&cnt[d.w >> 11], 1);
        }
        for (int e = end4 + t; e < hi; e += 1024) atomicAdd(&cnt[dei[e] >> 11], 1);
    } else {
        for (int e = lo + t; e < hi; e += 1024) atomicAdd(&cnt[dei[e] >> 11], 1);
    }
    __syncthreads();
    if (t < 64) {
        int c = cnt[t];
        basel[t] = c ? (atomicAdd(&curA[t], c) - t * CAPA) : 0;
        cnt[t] = 0;
    }
    __syncthreads();
    if (vec && end4 > lo4) {
        for (int e = lo + t; e < lo4; e += 1024) {
            int s = ei[e], d = dei[e]; int sp = d >> 11;
            int off = basel[sp] + atomicAdd(&cnt[sp], 1);
            if (off < CAPA) bufA[sp * CAPA + off] = (unsigned)s | ((unsigned)(d & 2047) << 17);
        }
        const int4* sei4 = (const int4*)ei;
        const int4* dei4 = (const int4*)dei;
        for (int v = (lo4 >> 2) + t; v < (end4 >> 2); v += 1024) {
            int4 sv = sei4[v]; int4 dv = dei4[v];
            int s0 = dv.x >> 11, s1 = dv.y >> 11, s2 = dv.z >> 11, s3 = dv.w >> 11;
            int o0 = basel[s0] + atomicAdd(&cnt[s0], 1);
            if (o0 < CAPA) bufA[s0 * CAPA + o0] = (unsigned)sv.x | ((unsigned)(dv.x & 2047) << 17);
            int o1 = basel[s1] + atomicAdd(&cnt[s1], 1);
            if (o1 < CAPA) bufA[s1 * CAPA + o1] = (unsigned)sv.y | ((unsigned)(dv.y & 2047) << 17);
            int o2 = basel[s2] + atomicAdd(&cnt[s2], 1);
            if (o2 < CAPA) bufA[s2 * CAPA + o2] = (unsigned)sv.z | ((unsigned)(dv.z & 2047) << 17);
            int o3 = basel[s3] + atomicAdd(&cnt[s3], 1);
            if (o3 < CAPA) bufA[s3 * CAPA + o3] = (unsigned)sv.w | ((unsigned)(dv.w & 2047) << 17);
        }
        for (int e = end4 + t; e < hi; e += 1024) {
            int s = ei[e], d = dei[e]; int sp = d >> 11;
            int off = basel[sp] + atomicAdd(&cnt[sp], 1);
            if (off < CAPA) bufA[sp * CAPA + off] = (unsigned)s | ((unsigned)(d & 2047) << 17);
        }
    } else {
        for (int e = lo + t; e < hi; e += 1024) {
            int s = ei[e], d = dei[e]; int sp = d >> 11;
            int off = basel[sp] + atomicAdd(&cnt[sp], 1);
            if (off < CAPA) bufA[sp * CAPA + off] = (unsigned)s | ((unsigned)(d & 2047) << 17);
        }
    }
}

// Pass B: 8 blocks per super; re-scatter into 16 final 128-node buckets.
__global__ void scatterB(const int* __restrict__ curA, int* __restrict__ curB,
                         const unsigned int* __restrict__ bufA,
                         unsigned int* __restrict__ pairs) {
    __shared__ int cnt[16];
    __shared__ int basel[16];
    int t = threadIdx.x;
    int sp = blockIdx.x >> 3;
    int part = blockIdx.x & 7;
    int base = sp * CAPA;
    int fill = min(curA[sp] - base, CAPA);
    if (fill <= 0) return;
    int lo = (fill * part) >> 3;
    int hi = (fill * (part + 1)) >> 3;
    for (int c0 = lo; c0 < hi; c0 += 8192) {
        int cend = min(hi, c0 + 8192);
        if (t < 16) cnt[t] = 0;
        __syncthreads();
        for (int i = c0 + t; i < cend; i += 1024)
            atomicAdd(&cnt[(bufA[base + i] >> 24) & 15], 1);
        __syncthreads();
        if (t < 16) {
            int c = cnt[t];
            int bkg = (sp << 4) + t;
            basel[t] = c ? (atomicAdd(&curB[bkg], c) - (bkg << 13)) : 0;
            cnt[t] = 0;
        }
        __syncthreads();
        for (int i = c0 + t; i < cend; i += 1024) {
            unsigned p = bufA[base + i];
            int b16 = (p >> 24) & 15;
            int off = basel[b16] + atomicAdd(&cnt[b16], 1);
            if (off < CAPG) pairs[(((sp << 4) + b16) << 13) + off] = p & 0x00FFFFFFu;
        }
        __syncthreads();
    }
}

// Layer-1: single-chunk sort + batched accumulate; persists gsorted + bmeta.
// 512 threads: 4 lanes own dst g; each lane walks stride-4, batch-8 x-gather.
__global__ __launch_bounds__(512, 8)
void l1_comb(const float* __restrict__ x,
             const int* __restrict__ curB,
             const unsigned int* __restrict__ pairs,
             unsigned int* __restrict__ gsorted, int* __restrict__ bmeta,
             const float* __restrict__ consts,
             const float* __restrict__ W1, const float* __restrict__ b1,
             const float* __restrict__ W2,
             const float* __restrict__ as2, const float* __restrict__ ad2,
             float* __restrict__ h2, float* __restrict__ als2,
             float* __restrict__ ald2, int N) {
    __shared__ unsigned sbuf[CAPS];
    __shared__ int hcnt[128], offs[128], hcur[128];
    __shared__ float xl[128];
    int t = threadIdx.x;
    int bk = blockIdx.x;
    int node0 = bk << 7;
    int nw = min(128, N - node0);
    if (t < 128) xl[t] = (t < nw) ? x[node0 + t] : 0.f;
    float S[4], D[4];
    #pragma unroll
    for (int h = 0; h < 4; ++h) { S[h] = consts[h]; D[h] = consts[4 + h]; }
    int base = bk << 13;
    int clen = min(curB[bk] - base, CAPG);
    int clen6 = min(clen, 6144);
    int g = t >> 2, jj = t & 3;
    // stage first 6144 pairs in regs; remainder read direct (rare tail)
    unsigned pr[12];
    #pragma unroll
    for (int k = 0; k < 12; ++k) {
        int idx = t + (k << 9);
        pr[k] = (idx < clen6) ? pairs[base + idx] : 0xFFFFFFFFu;
    }
    if (t < 128) hcnt[t] = 0;
    __syncthreads();
    #pragma unroll
    for (int k = 0; k < 12; ++k)
        if (pr[k] != 0xFFFFFFFFu) atomicAdd(&hcnt[pr[k] >> 17], 1);
    for (int idx = 6144 + t; idx < clen; idx += 512)
        atomicAdd(&hcnt[pairs[base + idx] >> 17], 1);
    __syncthreads();
    if (t < 64) {                          // wave-0 shfl scan of 128 bins
        int h0 = hcnt[2 * t], h1 = hcnt[2 * t + 1];
        int s = h0 + h1, sc_ = s;
        #pragma unroll
        for (int o = 1; o < 64; o <<= 1) {
            int u = __shfl_up(sc_, o);
            if (t >= o) sc_ += u;
        }
        int excl = sc_ - s;
        offs[2 * t] = excl;          hcur[2 * t] = excl;
        offs[2 * t + 1] = excl + h0; hcur[2 * t + 1] = excl + h0;
    }
    __syncthreads();
    #pragma unroll
    for (int k = 0; k < 12; ++k)
        if (pr[k] != 0xFFFFFFFFu) {
            int loc = atomicAdd(&hcur[pr[k] >> 17], 1);
            sbuf[loc] = pr[k];
        }
    for (int idx = 6144 + t; idx < clen; idx += 512) {
        unsigned p = pairs[base + idx];
        int loc = atomicAdd(&hcur[p >> 17], 1);
        sbuf[loc] = p;
    }
    __syncthreads();
    // persist sorted runs + meta for layer-2
    for (int i = t; i < clen; i += 512) gsorted[base + i] = sbuf[i];
    if (t < 128) bmeta[(bk << 7) + t] = offs[t] | (hcnt[t] << 14);
    // accumulate: 4 lanes own dst g, stride-4 walk, batch-8 x-gather
    float xd = xl[g];
    float sacc[4] = {0.f, 0.f, 0.f, 0.f};
    float tacc[4] = {0.f, 0.f, 0.f, 0.f};
    int st = offs[g], en = st + hcnt[g];
    int i = st + jj;
    while (i + 28 < en) {                  // 8 edges: i, i+4, ..., i+28
        unsigned p0 = sbuf[i],      p1 = sbuf[i + 4],  p2 = sbuf[i + 8],
                 p3 = sbuf[i + 12], p4 = sbuf[i + 16], p5 = sbuf[i + 20],
                 p6 = sbuf[i + 24], p7 = sbuf[i + 28];
        float x0 = x[p0 & 131071u], x1 = x[p1 & 131071u];
        float x2 = x[p2 & 131071u], x3 = x[p3 & 131071u];
        float x4 = x[p4 & 131071u], x5 = x[p5 & 131071u];
        float x6 = x[p6 & 131071u], x7 = x[p7 & 131071u];
        float xs_[8] = {x0, x1, x2, x3, x4, x5, x6, x7};
        #pragma unroll
        for (int q = 0; q < 8; ++q) {
            float xs = xs_[q];
            #pragma unroll
            for (int h = 0; h < 4; ++h) {
                float v = xs * S[h] + xd * D[h];
                v = (v > 0.f) ? v : NEG_SLOPE * v;
                float w = __expf(v);
                sacc[h] += w;
                tacc[h] = fmaf(w, xs, tacc[h]);
            }
        }
        i += 32;
    }
    for (; i < en; i += 4) {
        float xs = x[sbuf[i] & 131071u];
        #pragma unroll
        for (int h = 0; h < 4; ++h) {
            float v = xs * S[h] + xd * D[h];
            v = (v > 0.f) ? v : NEG_SLOPE * v;
            float w = __expf(v);
            sacc[h] += w;
            tacc[h] = fmaf(w, xs, tacc[h]);
        }
    }
    #pragma unroll
    for (int h = 0; h < 4; ++h) {
        sacc[h] += __shfl_xor(sacc[h], 1); sacc[h] += __shfl_xor(sacc[h], 2);
        tacc[h] += __shfl_xor(tacc[h], 1); tacc[h] += __shfl_xor(tacc[h], 2);
    }
    if (jj == 0 && g < nw) {
        int n = node0 + g;
        float xn = xd;
        float o[8];
        #pragma unroll
        for (int c = 0; c < 8; ++c) o[c] = 0.f;
        #pragma unroll
        for (int h = 0; h < 4; ++h) {
            float v = xn * (S[h] + D[h]);       // self-loop
            v = (v > 0.f) ? v : NEG_SLOPE * v;
            float ww = __expf(v);
            float s1 = ww + sacc[h];
            float t1 = ww * xn + tacc[h];
            float tt = t1 / s1;
            #pragma unroll
            for (int c = 0; c < 8; ++c) {
                float rr = fmaxf(tt * W1[h * 8 + c] + b1[h * 8 + c], 0.f);
                #pragma unroll
                for (int c2 = 0; c2 < 8; ++c2) o[c2] += rr * W2[(h * 8 + c) * 8 + c2];
            }
        }
        float as = 0.f, ad = 0.f;
        #pragma unroll
        for (int c = 0; c < 8; ++c) { as += o[c] * as2[c]; ad += o[c] * ad2[c]; }
        float4* hv = (float4*)&h2[(size_t)n * 8];
        hv[0] = make_float4(o[0], o[1], o[2], o[3]);
        hv[1] = make_float4(o[4], o[5], o[6], o[7]);
        als2[n] = as;
        ald2[n] = ad;
    }
}

// Layer-2: channel-parallel, no sort, batch-8 gathers (16 outstanding/thread).
// 512 threads: thread (g, j2) owns channels {2*j2, 2*j2+1} of dst g; the 4
// lanes of a group walk the same sorted run (run/als2 broadcast; h2 float2).
__global__ __launch_bounds__(512, 8)
void l2_comb(const unsigned int* __restrict__ gsorted,
             const int* __restrict__ bmeta,
             const float* __restrict__ als2, const float* __restrict__ ald2,
             const float* __restrict__ h2, const float* __restrict__ b2,
             float* __restrict__ out, int N) {
    __shared__ float adl[128];
    int t = threadIdx.x;
    int bk = blockIdx.x;
    int node0 = bk << 7;
    int nw = min(128, N - node0);
    if (t < 128) adl[t] = (t < nw) ? ald2[node0 + t] : 0.f;
    __syncthreads();
    int g = t >> 2, j2 = t & 3;
    if (g >= nw) return;
    int base = bk << 13;
    int pk = bmeta[(bk << 7) + g];
    int st = pk & 16383, cgn = pk >> 14;
    const unsigned* run = gsorted + base + st;
    const float2* h2f2 = (const float2*)h2;
    float adv = adl[g];
    float sw = 0.f, acc0 = 0.f, acc1 = 0.f;
    int i = 0;
    while (i + 8 <= cgn) {
        unsigned p0 = run[i],     p1 = run[i + 1], p2 = run[i + 2], p3 = run[i + 3],
                 p4 = run[i + 4], p5 = run[i + 5], p6 = run[i + 6], p7 = run[i + 7];
        int s0 = (int)(p0 & 131071u), s1 = (int)(p1 & 131071u);
        int s2 = (int)(p2 & 131071u), s3 = (int)(p3 & 131071u);
        int s4 = (int)(p4 & 131071u), s5 = (int)(p5 & 131071u);
        int s6 = (int)(p6 & 131071u), s7 = (int)(p7 & 131071u);
        float a0 = als2[s0], a1 = als2[s1], a2 = als2[s2], a3 = als2[s3];
        float a4 = als2[s4], a5 = als2[s5], a6 = als2[s6], a7 = als2[s7];
        float2 h0 = h2f2[s0 * 4 + j2], h1 = h2f2[s1 * 4 + j2];
        float2 h2v = h2f2[s2 * 4 + j2], h3 = h2f2[s3 * 4 + j2];
        float2 h4 = h2f2[s4 * 4 + j2], h5 = h2f2[s5 * 4 + j2];
        float2 h6 = h2f2[s6 * 4 + j2], h7 = h2f2[s7 * 4 + j2];
        float aa[8] = {a0, a1, a2, a3, a4, a5, a6, a7};
        float2 hh[8] = {h0, h1, h2v, h3, h4, h5, h6, h7};
        #pragma unroll
        for (int q = 0; q < 8; ++q) {
            float v = aa[q] + adv;
            v = (v > 0.f) ? v : NEG_SLOPE * v;
            float w = __expf(v);
            sw += w;
            acc0 = fmaf(w, hh[q].x, acc0);
            acc1 = fmaf(w, hh[q].y, acc1);
        }
        i += 8;
    }
    for (; i < cgn; ++i) {
        unsigned p = run[i];
        int s = (int)(p & 131071u);
        float a = als2[s];
        float2 hv = h2f2[s * 4 + j2];
        float v = a + adv;
        v = (v > 0.f) ? v : NEG_SLOPE * v;
        float w = __expf(v);
        sw += w;
        acc0 = fmaf(w, hv.x, acc0);
        acc1 = fmaf(w, hv.y, acc1);
    }
    // self-loop + output (coalesced: 4 lanes cover one 32B row)
    int n = node0 + g;
    float v = als2[n] + adv;
    v = (v > 0.f) ? v : NEG_SLOPE * v;
    float ww = __expf(v);
    float2 hs = h2f2[n * 4 + j2];
    float inv = 1.f / (sw + ww);
    float2* ov = (float2*)&out[(size_t)n * 8];
    ov[j2] = make_float2((acc0 + ww * hs.x) * inv + b2[2 * j2],
                         (acc1 + ww * hs.y) * inv + b2[2 * j2 + 1]);
}

// ---------------- fallback path (R2, atomic-based; known-correct) ----------------

__global__ void prep_consts(const float* __restrict__ W1,
                            const float* __restrict__ as1,
                            const float* __restrict__ ad1,
                            float* __restrict__ consts) {
    int t = threadIdx.x;
    if (t >= 8) return;
    int h = t & 3;
    const float* a = (t < 4) ? as1 : ad1;
    float s = 0.f;
    #pragma unroll
    for (int c = 0; c < 8; ++c)
        s += W1[h * 8 + c] * a[h * 8 + c];
    consts[t] = s;
}

__global__ void edge_pass1(const int* __restrict__ ei, const float* __restrict__ x,
                           const float* __restrict__ consts,
                           float* __restrict__ s1, float* __restrict__ t1, int E, int N) {
    int e = blockIdx.x * blockDim.x + threadIdx.x;
    if (e >= E + N) return;
    int src, dst;
    if (e < E) { src = ei[e]; dst = ei[E + e]; }
    else       { src = dst = e - E; }
    float xs = x[src], xd = x[dst];
    #pragma unroll
    for (int h = 0; h < 4; ++h) {
        float v = xs * consts[h] + xd * consts[4 + h];
        v = (v > 0.f) ? v : NEG_SLOPE * v;
        float w = __expf(v);
        atomicAdd(&s1[dst * 4 + h], w);
        atomicAdd(&t1[dst * 4 + h], w * xs);
    }
}

__global__ void node_mid(const float* __restrict__ s1, const float* __restrict__ t1,
                         const float* __restrict__ W1, const float* __restrict__ b1,
                         const float* __restrict__ W2,
                         const float* __restrict__ as2, const float* __restrict__ ad2,
                         float* __restrict__ h2, float* __restrict__ als2,
                         float* __restrict__ ald2, int N) {
    int n = blockIdx.x * blockDim.x + threadIdx.x;
    if (n >= N) return;
    float o[8];
    #pragma unroll
    for (int c = 0; c < 8; ++c) o[c] = 0.f;
    #pragma unroll
    for (int h = 0; h < 4; ++h) {
        float t = t1[n * 4 + h] / s1[n * 4 + h];
        #pragma unroll
        for (int c = 0; c < 8; ++c) {
            float r = fmaxf(t * W1[h * 8 + c] + b1[h * 8 + c], 0.f);
            #pragma unroll
            for (int c2 = 0; c2 < 8; ++c2) o[c2] += r * W2[(h * 8 + c) * 8 + c2];
        }
    }
    float as = 0.f, ad = 0.f;
    #pragma unroll
    for (int c = 0; c < 8; ++c) { h2[n * 8 + c] = o[c]; as += o[c] * as2[c]; ad += o[c] * ad2[c]; }
    als2[n] = as; ald2[n] = ad;
}

__global__ void edge_pass2(const int* __restrict__ ei, const float* __restrict__ als2,
                           const float* __restrict__ ald2, const float* __restrict__ h2,
                           float* __restrict__ s2, float* __restrict__ acc2, int E, int N) {
    int e = blockIdx.x * blockDim.x + threadIdx.x;
    if (e >= E + N) return;
    int src, dst;
    if (e < E) { src = ei[e]; dst = ei[E + e]; }
    else       { src = dst = e - E; }
    float v = als2[src] + ald2[dst];
    v = (v > 0.f) ? v : NEG_SLOPE * v;
    float w = __expf(v);
    atomicAdd(&s2[dst], w);
    const float4* hs = (const float4*)&h2[src * 8];
    float4 a = hs[0], bq = hs[1];
    float* acc = &acc2[dst * 8];
    atomicAdd(&acc[0], w * a.x);  atomicAdd(&acc[1], w * a.y);
    atomicAdd(&acc[2], w * a.z);  atomicAdd(&acc[3], w * a.w);
    atomicAdd(&acc[4], w * bq.x); atomicAdd(&acc[5], w * bq.y);
    atomicAdd(&acc[6], w * bq.z); atomicAdd(&acc[7], w * bq.w);
}

__global__ void node_out(const float* __restrict__ s2, const float* __restrict__ acc2,
                         const float* __restrict__ b2, float* __restrict__ out, int N) {
    int i = blockIdx.x * blockDim.x + threadIdx.x;
    if (i >= N * 8) return;
    out[i] = acc2[i] / s2[i >> 3] + b2[i & 7];
}

// ---------------------------------------------------------------------------

extern "C" void kernel_launch(void* const* d_in, const int* in_sizes, int n_in,
                              void* d_out, int out_size, void* d_ws, size_t ws_size,
                              hipStream_t stream) {
    const float* x   = (const float*)d_in[0];
    const int*   ei  = (const int*)d_in[1];
    const float* W1  = (const float*)d_in[2];
    const float* as1 = (const float*)d_in[3];
    const float* ad1 = (const float*)d_in[4];
    const float* b1  = (const float*)d_in[5];
    const float* W2  = (const float*)d_in[6];
    const float* as2 = (const float*)d_in[7];
    const float* ad2 = (const float*)d_in[8];
    const float* b2  = (const float*)d_in[9];
    float* out = (float*)d_out;

    const int N = in_sizes[0];          // 100000
    const int E = in_sizes[1] / 2;      // 3200000
    const int NBK = (N + 127) >> 7;     // 782 buckets of 128 nodes

    float* ws = (float*)d_ws;
    size_t need = ((size_t)16 + 64 + 1024 + 131072 + 10 * (size_t)N
                   + 2 * (size_t)1024 * CAPG + (size_t)64 * CAPA) * sizeof(float);

    if (N <= 131072 && ws_size >= need) {
        float*    consts  = ws;                               // 16
        int*      curA    = (int*)(ws + 16);                  // 64
        int*      curB    = curA + 64;                        // 1024
        int*      bmeta   = curB + 1024;                      // 131072
        float*    als2    = (float*)(bmeta + 131072);         // N
        float*    ald2    = als2 + N;                         // N
        float*    h2      = ald2 + N;                         // 8N
        unsigned* pairs   = (unsigned*)(h2 + 8 * (size_t)N);  // 1024*CAPG
        unsigned* gsorted = pairs + (size_t)1024 * CAPG;      // 1024*CAPG
        unsigned* bufA    = gsorted + (size_t)1024 * CAPG;    // 64*CAPA

        init_cc<<<1, 1024, 0, stream>>>(curA, curB, W1, as1, ad1, consts);
        scatterA<<<256, 1024, 0, stream>>>(ei, curA, bufA, E);
        scatterB<<<512, 1024, 0, stream>>>(curA, curB, bufA, pairs);
        l1_comb<<<NBK, 512, 0, stream>>>(x, curB, pairs, gsorted, bmeta, consts,
                                         W1, b1, W2, as2, ad2, h2, als2, ald2, N);
        l2_comb<<<NBK, 512, 0, stream>>>(gsorted, bmeta, als2, ald2, h2, b2, out, N);
    } else {
        // fallback: R2 atomic path (10.8 MB ws, known-correct)
        float* consts = ws;
        float* s1   = ws + 16;
        float* t1   = s1 + 4 * (size_t)N;
        float* h2   = t1 + 4 * (size_t)N;
        float* als2 = h2 + 8 * (size_t)N;
        float* ald2 = als2 + (size_t)N;
        float* s2   = ald2 + (size_t)N;
        float* acc2 = s2 + (size_t)N;

        hipMemsetAsync(ws, 0, (16 + 8 * (size_t)N) * sizeof(float), stream);
        hipMemsetAsync(s2, 0, 9 * (size_t)N * sizeof(float), stream);
        prep_consts<<<1, 64, 0, stream>>>(W1, as1, ad1, consts);
        int total = E + N;
        edge_pass1<<<(total + 255) / 256, 256, 0, stream>>>(ei, x, consts, s1, t1, E, N);
        node_mid<<<(N + 255) / 256, 256, 0, stream>>>(s1, t1, W1, b1, W2, as2, ad2, h2, als2, ald2, N);
        edge_pass2<<<(total + 255) / 256, 256, 0, stream>>>(ei, als2, ald2, h2, s2, acc2, E, N);
        node_out<<<(N * 8 + 255) / 256, 256, 0, stream>>>(s2, acc2, b2, out, N);
    }
}